// Round 6
// baseline (114.900 us; speedup 1.0000x reference)
//
#include <hip/hip_runtime.h>
#include <hip/hip_bf16.h>

// B=8192, D=1024, C=90, K=16.
// Two kernels, no LDS tiles, no barriers in the hot path:
//  (1) bin_labels: deterministic ballot-binning of sample indices by class;
//      also zeroes the integer loss accumulator + done counter (graph-replay
//      safe: runs every launch).
//  (2) dots_loss: wave = 4 same-class samples; centers read DIRECTLY from
//      global (L2-resident; same-class blocks pinned to one XCD via
//      blockIdx%8 == class%8 so each XCD caches ~12 classes = 768 KB).
//      Full-D dot in registers, DPP+shuffle value-halving reduction,
//      in-wave epilogue, order-invariant fixed-point atomic accumulation,
//      last-done wave writes the mean. Deterministic (integer adds commute).

#define B_SAMP  8192
#define D_DIM   1024
#define K_SUB   16
#define C_CLS   90
#define CAPC    12              // 16-sample chunks per class (cap 192)
#define SPB     16
#define LISTCAP 192
#define F4_ROW  256
#define NSLOT   12              // ceil(90/8) classes per XCD lane
#define NBLK    (8 * NSLOT * CAPC)   // 1152
#define NWAVES  (NBLK * 4)           // 4608
#define SCALE   4398046511104.0      // 2^42

// ws layout (bytes)
#define OFF_SUM    0            // u64 scaled loss sum
#define OFF_DONE   8            // u32 done counter
#define OFF_COUNTS 64           // 90 ints
#define OFF_LISTS  4096         // 90*192 ints

template <int CTRL>
__device__ __forceinline__ float dpp_qperm(float v) {
    // quad_perm DPP: full-rate VALU lane permute (stays off the DS pipe)
    return __int_as_float(__builtin_amdgcn_update_dpp(
        0, __float_as_int(v), CTRL, 0xF, 0xF, true));
}

__device__ __forceinline__ float dot16(float4 c0, float4 c1, float4 c2, float4 c3,
                                       float4 y0, float4 y1, float4 y2, float4 y3)
{
    float t = 0.0f;
    t = fmaf(y0.x, c0.x, t); t = fmaf(y0.y, c0.y, t);
    t = fmaf(y0.z, c0.z, t); t = fmaf(y0.w, c0.w, t);
    t = fmaf(y1.x, c1.x, t); t = fmaf(y1.y, c1.y, t);
    t = fmaf(y1.z, c1.z, t); t = fmaf(y1.w, c1.w, t);
    t = fmaf(y2.x, c2.x, t); t = fmaf(y2.y, c2.y, t);
    t = fmaf(y2.z, c2.z, t); t = fmaf(y2.w, c2.w, t);
    t = fmaf(y3.x, c3.x, t); t = fmaf(y3.y, c3.y, t);
    t = fmaf(y3.z, c3.z, t); t = fmaf(y3.w, c3.w, t);
    return t;
}

// 16-lane-group epilogue: lane holds d for k=kmap within its 16-group.
// Returns per-sample loss replicated across the group.
__device__ __forceinline__ float sample_loss16(float r, int kmap)
{
    const float d = 1.0f - r;
    float S = d;
    S += __shfl_xor(S, 1, 64);
    S += __shfl_xor(S, 2, 64);
    S += __shfl_xor(S, 4, 64);
    S += __shfl_xor(S, 8, 64);
    float dmin = d;
    dmin = fminf(dmin, __shfl_xor(dmin, 1, 64));
    dmin = fminf(dmin, __shfl_xor(dmin, 2, 64));
    dmin = fminf(dmin, __shfl_xor(dmin, 4, 64));
    dmin = fminf(dmin, __shfl_xor(dmin, 8, 64));
    // first-min k (matches jnp.argmin): smallest kmap among lanes at dmin
    int cand = (d == dmin) ? kmap : 99;
    cand = min(cand, __shfl_xor(cand, 1, 64));
    cand = min(cand, __shfl_xor(cand, 2, 64));
    cand = min(cand, __shfl_xor(cand, 4, 64));
    cand = min(cand, __shfl_xor(cand, 8, 64));
    const float inv = 1.0f / S;
    float t = (kmap == cand) ? (d * d * inv)            // term1 (k == argmin)
                             : ((1.0f - d * inv) * d);  // term2
    t += __shfl_xor(t, 1, 64);
    t += __shfl_xor(t, 2, 64);
    t += __shfl_xor(t, 4, 64);
    t += __shfl_xor(t, 8, 64);
    return t;
}

// ---------------- Kernel 1: bin labels by class (90 blocks) ----------------
__global__ __launch_bounds__(256) void bin_labels(
    const int* __restrict__ labels,
    int*       __restrict__ counts,
    int*       __restrict__ lists,
    unsigned long long* __restrict__ sum_acc,
    unsigned int*       __restrict__ done_ctr)
{
    const int c    = blockIdx.x;
    const int tid  = threadIdx.x;
    const int wave = tid >> 6;
    const int lane = tid & 63;
    __shared__ int wcnt[4];

    if (c == 0 && tid == 0) { *sum_acc = 0ull; *done_ctr = 0u; }

    const int4* lv = reinterpret_cast<const int4*>(labels);

    int4 seg[8];
    int cnt = 0;
#pragma unroll
    for (int it = 0; it < 8; ++it) {
        seg[it] = lv[wave * 512 + it * 64 + lane];
        cnt += (seg[it].x == c) + (seg[it].y == c) + (seg[it].z == c) + (seg[it].w == c);
    }
#pragma unroll
    for (int off = 32; off > 0; off >>= 1) cnt += __shfl_xor(cnt, off, 64);
    if (lane == 0) wcnt[wave] = cnt;
    __syncthreads();

    int base = 0;
    for (int w = 0; w < wave; ++w) base += wcnt[w];
    const int total = wcnt[0] + wcnt[1] + wcnt[2] + wcnt[3];

#pragma unroll
    for (int it = 0; it < 8; ++it) {
        const int idx0 = (wave * 512 + it * 64 + lane) * 4;
        const int ls[4] = { seg[it].x, seg[it].y, seg[it].z, seg[it].w };
#pragma unroll
        for (int u = 0; u < 4; ++u) {
            const bool hit = (ls[u] == c);
            const unsigned long long m = __ballot(hit);
            if (hit) {
                const int pos = base + (int)__popcll(m & ((1ull << lane) - 1ull));
                if (pos < LISTCAP) lists[c * LISTCAP + pos] = idx0 + u;
            }
            base += (int)__popcll(m);
        }
    }
    if (tid == 0) counts[c] = (total <= LISTCAP) ? total : LISTCAP;
}

// ---------------- Kernel 2: dots + epilogue + global accumulate ----------------
__global__ __launch_bounds__(256, 2) void dots_loss(
    const float* __restrict__ x,
    const float* __restrict__ centers,
    const int*   __restrict__ counts,
    const int*   __restrict__ lists,
    unsigned long long* __restrict__ sum_acc,
    unsigned int*       __restrict__ done_ctr,
    float*              __restrict__ out)
{
    const int b     = blockIdx.x;
    const int xcd   = b & 7;
    const int t     = b >> 3;
    const int slot  = t % NSLOT;
    const int chunk = t / NSLOT;
    const int c     = xcd + 8 * slot;       // all blocks of class c share b%8
    const int tid   = threadIdx.x;
    const int wave  = tid >> 6;
    const int lane  = tid & 63;

    float wl = 0.0f;

    int nw = 0;
    if (c < C_CLS) {
        const int cnt = counts[c];
        nw = cnt - (chunk * SPB + wave * 4);
        if (nw > 4) nw = 4;
    }

    if (nw > 0) {
        const int* ml = lists + c * LISTCAP + chunk * SPB + wave * 4;
        int ids[4];
        ids[0] = ml[0];
#pragma unroll
        for (int s = 1; s < 4; ++s) ids[s] = (s < nw) ? ml[s] : ids[0];

        const float4* xv = reinterpret_cast<const float4*>(x);
        const float4* cb = reinterpret_cast<const float4*>(centers)
                         + (size_t)c * (K_SUB * F4_ROW);

        float4 x0[4], x1[4], x2[4], x3[4];
#pragma unroll
        for (int s = 0; s < 4; ++s) {
            const size_t xo = (size_t)ids[s] * F4_ROW;
            x0[s] = xv[xo + lane];
            x1[s] = xv[xo + 64 + lane];
            x2[s] = xv[xo + 128 + lane];
            x3[s] = xv[xo + 192 + lane];
        }

        float a0[K_SUB], a1[K_SUB], a2[K_SUB], a3[K_SUB];
#pragma unroll 2
        for (int k = 0; k < K_SUB; ++k) {
            const float4 c0 = cb[k * F4_ROW + lane];
            const float4 c1 = cb[k * F4_ROW + 64 + lane];
            const float4 c2 = cb[k * F4_ROW + 128 + lane];
            const float4 c3 = cb[k * F4_ROW + 192 + lane];
            a0[k] = dot16(c0, c1, c2, c3, x0[0], x1[0], x2[0], x3[0]);
            a1[k] = dot16(c0, c1, c2, c3, x0[1], x1[1], x2[1], x3[1]);
            a2[k] = dot16(c0, c1, c2, c3, x0[2], x1[2], x2[2], x3[2]);
            a3[k] = dot16(c0, c1, c2, c3, x0[3], x1[3], x2[3], x3[3]);
        }

        // Value-halving reduction: xor1/xor2 on VALU (DPP), xor4/8/16/32 shuffles.
        const bool b0 = (lane & 1) != 0;
        const bool b1 = (lane & 2) != 0;
        const bool b2 = (lane & 4) != 0;
        const bool b3 = (lane & 8) != 0;
        const int kmap = 8 * (lane & 1) + 4 * ((lane >> 1) & 1)
                       + 2 * ((lane >> 2) & 1) + ((lane >> 3) & 1);

#define REDUCE16(A, OUT)                                                      \
    {                                                                         \
        _Pragma("unroll")                                                     \
        for (int j = 0; j < 8; ++j) {                                         \
            const float send = b0 ? A[j] : A[j + 8];                          \
            const float recv = dpp_qperm<0xB1>(send);       /* xor 1 */       \
            A[j] = (b0 ? A[j + 8] : A[j]) + recv;                             \
        }                                                                     \
        _Pragma("unroll")                                                     \
        for (int j = 0; j < 4; ++j) {                                         \
            const float send = b1 ? A[j] : A[j + 4];                          \
            const float recv = dpp_qperm<0x4E>(send);       /* xor 2 */       \
            A[j] = (b1 ? A[j + 4] : A[j]) + recv;                             \
        }                                                                     \
        _Pragma("unroll")                                                     \
        for (int j = 0; j < 2; ++j) {                                         \
            const float send = b2 ? A[j] : A[j + 2];                          \
            const float recv = __shfl_xor(send, 4, 64);                       \
            A[j] = (b2 ? A[j + 2] : A[j]) + recv;                             \
        }                                                                     \
        {                                                                     \
            const float send = b3 ? A[0] : A[1];                              \
            const float recv = __shfl_xor(send, 8, 64);                       \
            A[0] = (b3 ? A[1] : A[0]) + recv;                                 \
        }                                                                     \
        A[0] += __shfl_xor(A[0], 16, 64);                                     \
        A[0] += __shfl_xor(A[0], 32, 64);                                     \
        OUT = A[0];                                                           \
    }

        float r0, r1, r2, r3;
        REDUCE16(a0, r0)
        REDUCE16(a1, r1)
        REDUCE16(a2, r2)
        REDUCE16(a3, r3)
#undef REDUCE16

        // In-wave epilogue (all lanes participate; nw is wave-uniform)
        {
            const float l0 = sample_loss16(r0, kmap);
            const float l1 = sample_loss16(r1, kmap);
            const float l2 = sample_loss16(r2, kmap);
            const float l3 = sample_loss16(r3, kmap);
            wl = l0;
            if (1 < nw) wl += l1;
            if (2 < nw) wl += l2;
            if (3 < nw) wl += l3;
        }
    }

    // Order-invariant fixed-point accumulation (deterministic) + last-done write.
    if (lane == 0) {
        const long long q = (wl != 0.0f) ? __double2ll_rn((double)wl * SCALE) : 0ll;
        if (q != 0) atomicAdd(sum_acc, (unsigned long long)q);
        __threadfence();
        const unsigned int old = atomicAdd(done_ctr, 1u);
        if (old == (unsigned int)(NWAVES - 1)) {
            const unsigned long long tot = atomicAdd(sum_acc, 0ull);
            out[0] = (float)((double)(long long)tot * (1.0 / (SCALE * (double)B_SAMP)));
        }
    }
}

extern "C" void kernel_launch(void* const* d_in, const int* in_sizes, int n_in,
                              void* d_out, int out_size, void* d_ws, size_t ws_size,
                              hipStream_t stream)
{
    const float* x       = (const float*)d_in[0];
    const int*   labels  = (const int*)  d_in[1];
    const float* centers = (const float*)d_in[2];
    float*       out     = (float*)d_out;
    char*        ws      = (char*)d_ws;

    unsigned long long* sum_acc  = (unsigned long long*)(ws + OFF_SUM);
    unsigned int*       done_ctr = (unsigned int*)      (ws + OFF_DONE);
    int*                counts   = (int*)               (ws + OFF_COUNTS);
    int*                lists    = (int*)               (ws + OFF_LISTS);

    bin_labels<<<C_CLS, 256, 0, stream>>>(labels, counts, lists, sum_acc, done_ctr);
    dots_loss <<<NBLK,  256, 0, stream>>>(x, centers, counts, lists, sum_acc, done_ctr, out);
}

// Round 7
// 30.379 us; speedup vs baseline: 3.7822x; 3.7822x over previous
//
#include <hip/hip_runtime.h>

// B=8192, D=1024, C=90, K=16.
// Three kernels, deterministic, no global atomics:
//  (1) bin_labels: ballot-binning of sample indices by class (90 blocks).
//  (2) dots_loss3: block = (class, 16-sample chunk). D-SPLIT across the 4
//      waves: wave w holds its D-quarter of ALL 16 sub-centers in 64 VGPRs
//      (staged once from L2). Per sample: one coalesced float4 x-load
//      (depth-3 prefetch), 64 FMAs, DPP+shuffle REDUCE16, one LDS write.
//      Tiny LDS epilogue combines the 4 quarter-partials per sample and
//      computes the loss -> one partial per block. No 32KB LDS tile, no
//      staging barriers in the hot loop, x streams continuously from HBM.
//  (3) reduce_final: 1080 partials -> mean.

#define B_SAMP  8192
#define D_DIM   1024
#define K_SUB   16
#define C_CLS   90
#define CAPC    12              // 16-sample chunks per class (capacity 192)
#define SPB     16
#define LISTCAP 192
#define F4_ROW  256
#define NBLK    (C_CLS * CAPC)  // 1080

// ws layout (bytes)
#define OFF_COUNTS 0            // 90 ints
#define OFF_LISTS  4096         // 90*192 ints
#define OFF_PART   (1u << 20)   // 1080 floats

template <int CTRL>
__device__ __forceinline__ float dpp_qperm(float v) {
    // quad_perm DPP: full-rate VALU lane permute (stays off the DS pipe)
    return __int_as_float(__builtin_amdgcn_update_dpp(
        0, __float_as_int(v), CTRL, 0xF, 0xF, true));
}

// 16-lane-group epilogue: lane holds d for k=kk within its 16-group.
// Returns the per-sample loss replicated across the group.
__device__ __forceinline__ float sample_loss16(float r, int kk)
{
    const float d = 1.0f - r;
    float S = d;
    S += __shfl_xor(S, 1, 64);
    S += __shfl_xor(S, 2, 64);
    S += __shfl_xor(S, 4, 64);
    S += __shfl_xor(S, 8, 64);
    float dmin = d;
    dmin = fminf(dmin, __shfl_xor(dmin, 1, 64));
    dmin = fminf(dmin, __shfl_xor(dmin, 2, 64));
    dmin = fminf(dmin, __shfl_xor(dmin, 4, 64));
    dmin = fminf(dmin, __shfl_xor(dmin, 8, 64));
    // first-min k (matches jnp.argmin): smallest k among lanes at dmin
    int cand = (d == dmin) ? kk : 99;
    cand = min(cand, __shfl_xor(cand, 1, 64));
    cand = min(cand, __shfl_xor(cand, 2, 64));
    cand = min(cand, __shfl_xor(cand, 4, 64));
    cand = min(cand, __shfl_xor(cand, 8, 64));
    const float inv = 1.0f / S;
    float t = (kk == cand) ? (d * d * inv)            // term1 (k == argmin)
                           : ((1.0f - d * inv) * d);  // term2
    t += __shfl_xor(t, 1, 64);
    t += __shfl_xor(t, 2, 64);
    t += __shfl_xor(t, 4, 64);
    t += __shfl_xor(t, 8, 64);
    return t;
}

// ---------------- Kernel 1: bin labels by class (90 blocks) ----------------
__global__ __launch_bounds__(256) void bin_labels(
    const int* __restrict__ labels,
    int*       __restrict__ counts,
    int*       __restrict__ lists)
{
    const int c    = blockIdx.x;
    const int tid  = threadIdx.x;
    const int wave = tid >> 6;
    const int lane = tid & 63;
    __shared__ int wcnt[4];

    const int4* lv = reinterpret_cast<const int4*>(labels);

    int4 seg[8];
    int cnt = 0;
#pragma unroll
    for (int it = 0; it < 8; ++it) {
        seg[it] = lv[wave * 512 + it * 64 + lane];
        cnt += (seg[it].x == c) + (seg[it].y == c) + (seg[it].z == c) + (seg[it].w == c);
    }
#pragma unroll
    for (int off = 32; off > 0; off >>= 1) cnt += __shfl_xor(cnt, off, 64);
    if (lane == 0) wcnt[wave] = cnt;
    __syncthreads();

    int base = 0;
    for (int w = 0; w < wave; ++w) base += wcnt[w];
    const int total = wcnt[0] + wcnt[1] + wcnt[2] + wcnt[3];

#pragma unroll
    for (int it = 0; it < 8; ++it) {
        const int idx0 = (wave * 512 + it * 64 + lane) * 4;
        const int ls[4] = { seg[it].x, seg[it].y, seg[it].z, seg[it].w };
#pragma unroll
        for (int u = 0; u < 4; ++u) {
            const bool hit = (ls[u] == c);
            const unsigned long long m = __ballot(hit);
            if (hit) {
                const int pos = base + (int)__popcll(m & ((1ull << lane) - 1ull));
                if (pos < LISTCAP) lists[c * LISTCAP + pos] = idx0 + u;
            }
            base += (int)__popcll(m);
        }
    }
    if (tid == 0) counts[c] = (total <= LISTCAP) ? total : LISTCAP;
}

// ---------------- Kernel 2: D-split dots + in-block loss ----------------
__global__ __launch_bounds__(256) void dots_loss3(
    const float* __restrict__ x,
    const float* __restrict__ centers,
    const int*   __restrict__ counts,
    const int*   __restrict__ lists,
    float*       __restrict__ partials)
{
    const int blk   = blockIdx.x;
    const int c     = blk / CAPC;
    const int chunk = blk % CAPC;
    const int tid   = threadIdx.x;
    const int wv    = tid >> 6;
    const int lane  = tid & 63;

    const int cnt   = counts[c];
    const int cbase = chunk * SPB;
    if (cbase >= cnt) {                       // no work: still write the partial
        if (tid == 0) partials[blk] = 0.0f;
        return;
    }

    __shared__ int   slist[SPB];
    __shared__ float sdots[4][SPB][K_SUB + 1];   // +1 pad
    __shared__ float wsum[4];

    // stage this chunk's sample ids (pad with last valid id)
    if (tid < SPB) {
        int p = cbase + tid;
        if (p >= cnt) p = cnt - 1;
        slist[tid] = lists[c * LISTCAP + p];
    }

    // stage this wave's D-quarter of all 16 sub-centers into 64 VGPRs
    // (16 independent coalesced float4 loads, L2-resident after first touch)
    const float4* cg = reinterpret_cast<const float4*>(centers)
                     + (size_t)c * (K_SUB * F4_ROW) + wv * 64 + lane;
    float4 cw[K_SUB];
#pragma unroll
    for (int k = 0; k < K_SUB; ++k) cw[k] = cg[k * F4_ROW];

    __syncthreads();                          // slist ready (also drains cw)

    const float4* xq = reinterpret_cast<const float4*>(x) + (wv * 64 + lane);

    // depth-3 x prefetch pipeline
    float4 x0 = xq[(size_t)slist[0] * F4_ROW];
    float4 x1 = xq[(size_t)slist[1] * F4_ROW];
    float4 x2 = xq[(size_t)slist[2] * F4_ROW];

    const bool b0 = (lane & 1) != 0;
    const bool b1 = (lane & 2) != 0;
    const bool b2 = (lane & 4) != 0;
    const bool b3 = (lane & 8) != 0;
    const int kmap = 8 * (lane & 1) + 4 * ((lane >> 1) & 1)
                   + 2 * ((lane >> 2) & 1) + ((lane >> 3) & 1);

#define REDUCE16(A, OUT)                                                      \
    {                                                                         \
        _Pragma("unroll")                                                     \
        for (int j = 0; j < 8; ++j) {                                         \
            const float send = b0 ? A[j] : A[j + 8];                          \
            const float recv = dpp_qperm<0xB1>(send);       /* xor 1 */       \
            A[j] = (b0 ? A[j + 8] : A[j]) + recv;                             \
        }                                                                     \
        _Pragma("unroll")                                                     \
        for (int j = 0; j < 4; ++j) {                                         \
            const float send = b1 ? A[j] : A[j + 4];                          \
            const float recv = dpp_qperm<0x4E>(send);       /* xor 2 */       \
            A[j] = (b1 ? A[j + 4] : A[j]) + recv;                             \
        }                                                                     \
        _Pragma("unroll")                                                     \
        for (int j = 0; j < 2; ++j) {                                         \
            const float send = b2 ? A[j] : A[j + 2];                          \
            const float recv = __shfl_xor(send, 4, 64);                       \
            A[j] = (b2 ? A[j + 2] : A[j]) + recv;                             \
        }                                                                     \
        {                                                                     \
            const float send = b3 ? A[0] : A[1];                              \
            const float recv = __shfl_xor(send, 8, 64);                       \
            A[0] = (b3 ? A[1] : A[0]) + recv;                                 \
        }                                                                     \
        A[0] += __shfl_xor(A[0], 16, 64);                                     \
        A[0] += __shfl_xor(A[0], 32, 64);                                     \
        OUT = A[0];                                                           \
    }

#pragma unroll
    for (int s = 0; s < SPB; ++s) {
        const float4 xc = x0;
        x0 = x1; x1 = x2;
        if (s + 3 < SPB) x2 = xq[(size_t)slist[s + 3] * F4_ROW];

        float acc[K_SUB];
#pragma unroll
        for (int k = 0; k < K_SUB; ++k) {
            float t = xc.x * cw[k].x;
            t = fmaf(xc.y, cw[k].y, t);
            t = fmaf(xc.z, cw[k].z, t);
            t = fmaf(xc.w, cw[k].w, t);
            acc[k] = t;
        }

        float r;
        REDUCE16(acc, r)
        if (lane < 16) sdots[wv][s][kmap] = r;   // this wave's D-quarter partial
    }
#undef REDUCE16
    __syncthreads();                          // all quarter-partials in LDS

    // epilogue: wave wv handles samples s = wv*4 + (lane>>4); k = lane&15
    const int g  = lane >> 4;
    const int kk = lane & 15;
    const int s  = wv * 4 + g;
    const float r4 = sdots[0][s][kk] + sdots[1][s][kk]
                   + sdots[2][s][kk] + sdots[3][s][kk];
    const float lg = sample_loss16(r4, kk);
    float wl = (cbase + s < cnt) ? lg : 0.0f;   // gate padded samples
    wl += __shfl_xor(wl, 16, 64);               // sum the 4 groups of the wave
    wl += __shfl_xor(wl, 32, 64);
    if (lane == 0) wsum[wv] = wl;
    __syncthreads();
    if (tid == 0) partials[blk] = wsum[0] + wsum[1] + wsum[2] + wsum[3];
}

// ---------------- Kernel 3: final mean over 1080 block partials ----------------
__global__ __launch_bounds__(256) void reduce_final(
    const float* __restrict__ partials,
    float*       __restrict__ out)
{
    const int tid  = threadIdx.x;
    const int wave = tid >> 6;
    const int lane = tid & 63;
    float s = 0.0f;
    for (int i = tid; i < NBLK; i += 256) s += partials[i];
#pragma unroll
    for (int off = 32; off > 0; off >>= 1) s += __shfl_xor(s, off, 64);
    __shared__ float w[4];
    if (lane == 0) w[wave] = s;
    __syncthreads();
    if (tid == 0)
        out[0] = (w[0] + w[1] + w[2] + w[3]) * (1.0f / (float)B_SAMP);
}

extern "C" void kernel_launch(void* const* d_in, const int* in_sizes, int n_in,
                              void* d_out, int out_size, void* d_ws, size_t ws_size,
                              hipStream_t stream)
{
    const float* x       = (const float*)d_in[0];
    const int*   labels  = (const int*)  d_in[1];
    const float* centers = (const float*)d_in[2];
    float*       out     = (float*)d_out;
    char*        ws      = (char*)d_ws;

    int*   counts = (int*)  (ws + OFF_COUNTS);
    int*   lists  = (int*)  (ws + OFF_LISTS);
    float* parts  = (float*)(ws + OFF_PART);

    bin_labels  <<<C_CLS, 256, 0, stream>>>(labels, counts, lists);
    dots_loss3  <<<NBLK,  256, 0, stream>>>(x, centers, counts, lists, parts);
    reduce_final<<<1,     256, 0, stream>>>(parts, out);
}